// Round 1
// baseline (415.911 us; speedup 1.0000x reference)
//
#include <hip/hip_runtime.h>
#include <hip/hip_bf16.h>
#include <math.h>

typedef __bf16 bf16_t;
typedef __bf16 bf16x8 __attribute__((ext_vector_type(8)));
typedef float f32x4 __attribute__((ext_vector_type(4)));

#define BM 128
#define BN 128
#define BK 32

enum { EP_BF16 = 0, EP_SCORES = 1, EP_F32 = 2 };

__device__ __forceinline__ void gload_lds16(const void* g, void* l) {
  __builtin_amdgcn_global_load_lds(
      (const __attribute__((address_space(1))) void*)g,
      (__attribute__((address_space(3))) void*)l, 16, 0, 0);
}

// C[i][j] = sum_k A[i][k] * Bt[j][k]   (A: [M][K] row-major, Bt: [N][K] row-major)
// EP_BF16:   Cout bf16 [M][N]
// EP_SCORES: Cout f32  [M][N], v = acc*scale, causal -inf above diag
// EP_F32:    Cout f32  [M][N], causal => K truncated to row0+BM (probs zero beyond)
template <int EPI>
__launch_bounds__(256)
__global__ void gemm_bt(const bf16_t* __restrict__ A, const bf16_t* __restrict__ B,
                        void* __restrict__ Cout, int M, int N, int K,
                        const int* __restrict__ maskflag, float scale)
{
  __shared__ __align__(16) bf16_t Abuf[BM * BK];
  __shared__ __align__(16) bf16_t Bbuf[BN * BK];

  const int tid  = threadIdx.x;
  const int w    = tid >> 6;
  const int lane = tid & 63;
  const int bm   = blockIdx.y;
  const int bn   = blockIdx.x;
  const int row0 = bm * BM;
  const int col0 = bn * BN;

  const bool causal = (maskflag != nullptr) && (maskflag[0] == 0);

  if (EPI == EP_SCORES) {
    if (causal && col0 > row0 + (BM - 1)) {
      // fully masked tile: fill -inf, skip compute
      float* C = (float*)Cout;
      const float4 val = make_float4(-INFINITY, -INFINITY, -INFINITY, -INFINITY);
      for (int i = tid; i < BM * (BN / 4); i += 256) {
        const int r  = i >> 5;   // BN/4 = 32 float4 per row
        const int cg = i & 31;
        *(float4*)&C[(size_t)(row0 + r) * N + col0 + cg * 4] = val;
      }
      return;
    }
  }

  int Keff = K;
  if (EPI == EP_F32 && causal) Keff = min(K, row0 + BM);

  // staging: 8 chunks of 1KiB per operand; chunk = t*4 + w (wave-uniform LDS base)
  const int srow  = lane >> 2;        // row within 16-row chunk
  const int skoff = (lane & 3) * 8;   // k-offset in elements

  f32x4 acc[4][4] = {};

  const int wr   = w >> 1;            // wave row (2x2 wave grid, 64x64 per wave)
  const int wc   = w & 1;
  const int frow = lane & 15;         // fragment row (A) / col (B)
  const int fk   = (lane >> 4) * 8;   // fragment k-offset

  for (int kt = 0; kt < Keff; kt += BK) {
#pragma unroll
    for (int t = 0; t < 2; ++t) {
      const int chunk = t * 4 + w;
      const bf16_t* gA = A + (size_t)(row0 + chunk * 16 + srow) * K + kt + skoff;
      gload_lds16(gA, Abuf + chunk * 512);
      const bf16_t* gB = B + (size_t)(col0 + chunk * 16 + srow) * K + kt + skoff;
      gload_lds16(gB, Bbuf + chunk * 512);
    }
    asm volatile("s_waitcnt vmcnt(0)" ::: "memory");
    __syncthreads();

    bf16x8 af[4], bfr[4];
#pragma unroll
    for (int m = 0; m < 4; ++m)
      af[m] = *(const bf16x8*)&Abuf[(wr * 64 + m * 16 + frow) * BK + fk];
#pragma unroll
    for (int n = 0; n < 4; ++n)
      bfr[n] = *(const bf16x8*)&Bbuf[(wc * 64 + n * 16 + frow) * BK + fk];
#pragma unroll
    for (int m = 0; m < 4; ++m)
#pragma unroll
      for (int n = 0; n < 4; ++n)
        acc[m][n] = __builtin_amdgcn_mfma_f32_16x16x32_bf16(af[m], bfr[n], acc[m][n], 0, 0, 0);
    __syncthreads();
  }

  // C/D layout (m89-verified): col = lane&15, row = (lane>>4)*4 + reg
  const int cr = (lane >> 4) * 4;
  const int cc = lane & 15;
#pragma unroll
  for (int m = 0; m < 4; ++m) {
#pragma unroll
    for (int n = 0; n < 4; ++n) {
#pragma unroll
      for (int i = 0; i < 4; ++i) {
        const int r = row0 + wr * 64 + m * 16 + cr + i;
        const int c = col0 + wc * 64 + n * 16 + cc;
        float v = acc[m][n][i];
        if (EPI == EP_BF16) {
          ((bf16_t*)Cout)[(size_t)r * N + c] = (bf16_t)v;
        } else if (EPI == EP_SCORES) {
          v *= scale;
          if (causal && c > r) v = -INFINITY;
          ((float*)Cout)[(size_t)r * N + c] = v;
        } else {
          ((float*)Cout)[(size_t)r * N + c] = v;
        }
      }
    }
  }
}

__global__ void cvt_f32_bf16(const float* __restrict__ x, bf16_t* __restrict__ y, long n) {
  long i = ((long)blockIdx.x * blockDim.x + threadIdx.x) * 8;
  const long stride = (long)gridDim.x * blockDim.x * 8;
  for (; i < n; i += stride) {
    const float4 a = *(const float4*)(x + i);
    const float4 b = *(const float4*)(x + i + 4);
    bf16x8 o;
    o[0] = (__bf16)a.x; o[1] = (__bf16)a.y; o[2] = (__bf16)a.z; o[3] = (__bf16)a.w;
    o[4] = (__bf16)b.x; o[5] = (__bf16)b.y; o[6] = (__bf16)b.z; o[7] = (__bf16)b.w;
    *(bf16x8*)(y + i) = o;
  }
}

// WT[n][k] = (bf16) W[k][n]
__global__ void transpose_cvt(const float* __restrict__ W, bf16_t* __restrict__ WT, int Dm) {
  __shared__ float tile[32][33];
  const int bx = blockIdx.x;           // n tile
  const int by = blockIdx.y;           // k tile
  const int tx = threadIdx.x & 31;
  const int ty = threadIdx.x >> 5;     // 0..7
#pragma unroll
  for (int r = ty; r < 32; r += 8)
    tile[r][tx] = W[(size_t)(by * 32 + r) * Dm + bx * 32 + tx];
  __syncthreads();
#pragma unroll
  for (int r = ty; r < 32; r += 8)
    WT[(size_t)(bx * 32 + r) * Dm + by * 32 + tx] = (bf16_t)tile[tx][r];
}

// one block per row, n == 4096 (16 elements / thread)
__global__ void softmax_rows(const float* __restrict__ Sc, bf16_t* __restrict__ P, int n) {
  const int row = blockIdx.x;
  const int tid = threadIdx.x;
  const float* srow = Sc + (size_t)row * n;
  float v[16];
  float m = -INFINITY;
#pragma unroll
  for (int j = 0; j < 16; ++j) {
    v[j] = srow[tid + j * 256];
    m = fmaxf(m, v[j]);
  }
#pragma unroll
  for (int off = 32; off >= 1; off >>= 1) m = fmaxf(m, __shfl_xor(m, off));
  __shared__ float redm[4];
  __shared__ float reds[4];
  if ((tid & 63) == 0) redm[tid >> 6] = m;
  __syncthreads();
  m = fmaxf(fmaxf(redm[0], redm[1]), fmaxf(redm[2], redm[3]));
  float s = 0.f;
#pragma unroll
  for (int j = 0; j < 16; ++j) {
    v[j] = __expf(v[j] - m);
    s += v[j];
  }
#pragma unroll
  for (int off = 32; off >= 1; off >>= 1) s += __shfl_xor(s, off);
  if ((tid & 63) == 0) reds[tid >> 6] = s;
  __syncthreads();
  s = reds[0] + reds[1] + reds[2] + reds[3];
  const float inv = 1.f / s;
  bf16_t* prow = P + (size_t)row * n;
#pragma unroll
  for (int j = 0; j < 16; ++j) prow[tid + j * 256] = (bf16_t)(v[j] * inv);
}

extern "C" void kernel_launch(void* const* d_in, const int* in_sizes, int n_in,
                              void* d_out, int out_size, void* d_ws, size_t ws_size,
                              hipStream_t stream) {
  const float* ie = (const float*)d_in[0];  // input_embedding  [S,D]
  const float* qe = (const float*)d_in[1];  // query_embedding  [S,D]
  const float* Wq = (const float*)d_in[2];
  const float* Wk = (const float*)d_in[3];
  const float* Wv = (const float*)d_in[4];
  const int* mask = (const int*)d_in[5];    // include_mask (0 => causal)
  float* out = (float*)d_out;

  const int S = 4096, D = 2048;
  char* ws = (char*)d_ws;
  const size_t MB = 1u << 20;
  // persistent: q16/k16/vT16 (48 MiB)
  bf16_t* q16  = (bf16_t*)(ws + 0 * MB);
  bf16_t* k16  = (bf16_t*)(ws + 16 * MB);
  bf16_t* vT16 = (bf16_t*)(ws + 32 * MB);
  // temps (dead after QKV GEMMs), overlaid later by scores
  bf16_t* qe16 = (bf16_t*)(ws + 48 * MB);
  bf16_t* ie16 = (bf16_t*)(ws + 64 * MB);
  bf16_t* WqT  = (bf16_t*)(ws + 80 * MB);
  bf16_t* WkT  = (bf16_t*)(ws + 88 * MB);
  bf16_t* WvT  = (bf16_t*)(ws + 96 * MB);
  float*  scores = (float*)(ws + 48 * MB);   // 64 MiB, overlays qe16/ie16/W*T
  bf16_t* probs  = (bf16_t*)(ws + 112 * MB); // 32 MiB; peak ws use = 144 MiB

  // 1. casts
  cvt_f32_bf16<<<2048, 256, 0, stream>>>(qe, qe16, (long)S * D);
  cvt_f32_bf16<<<2048, 256, 0, stream>>>(ie, ie16, (long)S * D);
  transpose_cvt<<<dim3(D / 32, D / 32), 256, 0, stream>>>(Wq, WqT, D);
  transpose_cvt<<<dim3(D / 32, D / 32), 256, 0, stream>>>(Wk, WkT, D);
  transpose_cvt<<<dim3(D / 32, D / 32), 256, 0, stream>>>(Wv, WvT, D);

  // 2. QKV projections
  gemm_bt<EP_BF16><<<dim3(D / BN, S / BM), 256, 0, stream>>>(qe16, WqT, q16, S, D, D, nullptr, 1.f);
  gemm_bt<EP_BF16><<<dim3(D / BN, S / BM), 256, 0, stream>>>(ie16, WkT, k16, S, D, D, nullptr, 1.f);
  // vT[d][s] = sum_k Wv[k][d] * ie[s][k]  => A = WvT [D][D], Bt = ie16 [S][D]
  gemm_bt<EP_BF16><<<dim3(S / BN, D / BM), 256, 0, stream>>>(WvT, ie16, vT16, D, S, D, nullptr, 1.f);

  // 3. scores = (q @ k^T) * 0.1 with causal mask, fp32
  gemm_bt<EP_SCORES><<<dim3(S / BN, S / BM), 256, 0, stream>>>(q16, k16, scores, S, S, D, mask, 0.1f);

  // 4. row softmax -> bf16 probs
  softmax_rows<<<S, 256, 0, stream>>>(scores, probs, S);

  // 5. out = probs @ v  => A = probs [S][S], Bt = vT16 [D][S], causal-truncated K
  gemm_bt<EP_F32><<<dim3(D / BN, S / BM), 256, 0, stream>>>(probs, vT16, out, S, D, S, mask, 1.f);
}

// Round 2
// 289.794 us; speedup vs baseline: 1.4352x; 1.4352x over previous
//
#include <hip/hip_runtime.h>
#include <hip/hip_bf16.h>
#include <math.h>

typedef __bf16 bf16_t;
typedef __bf16 bf16x8 __attribute__((ext_vector_type(8)));
typedef float f32x4 __attribute__((ext_vector_type(4)));

enum { EP_BF16 = 0, EP_SCORES = 1, EP_F32 = 2 };

__device__ __forceinline__ void gload_lds16(const void* g, void* l) {
  __builtin_amdgcn_global_load_lds(
      (const __attribute__((address_space(1))) void*)g,
      (__attribute__((address_space(3))) void*)l, 16, 0, 0);
}

// ---------------------------------------------------------------------------
// Deep-pipelined GEMM core: C[row0+i][col0+j] = sum_k A[row0+i][k]*B[col0+j][k]
// A:[M][K], B:[N][K] row-major bf16. BK=32, BN=256, 8 waves (2Mx4N).
// TM = per-wave M-frags (8 -> BM=256, 4 -> BM=128).
// 4 LDS slots, stage depth 3 tiles ahead, counted vmcnt (8 / 6), T2 swizzle.
// ---------------------------------------------------------------------------

template <int TM, bool STG>
__device__ __forceinline__ void do_tile(char* smem, int slot, int sslot, size_t stoff,
                                        const char* const* gbase, const int* lbase,
                                        const int* aoff, const int* boff,
                                        f32x4 (&acc)[TM][4]) {
  bf16x8 bfr[4], af[4];
  if constexpr (TM == 8) {
    // phase 0: stage A-rounds of tile t+3, compute mh=0 quadrant (full K=32)
    if constexpr (STG) {
      gload_lds16(gbase[0] + stoff, smem + sslot + lbase[0]);
      gload_lds16(gbase[1] + stoff, smem + sslot + lbase[1]);
    }
#pragma unroll
    for (int n = 0; n < 4; ++n) bfr[n] = *(const bf16x8*)(smem + slot + boff[n]);
#pragma unroll
    for (int m = 0; m < 4; ++m) af[m] = *(const bf16x8*)(smem + slot + aoff[m]);
    __builtin_amdgcn_s_setprio(1);
#pragma unroll
    for (int m = 0; m < 4; ++m)
#pragma unroll
      for (int n = 0; n < 4; ++n)
        acc[m][n] = __builtin_amdgcn_mfma_f32_16x16x32_bf16(af[m], bfr[n], acc[m][n], 0, 0, 0);
    __builtin_amdgcn_s_setprio(0);
    if constexpr (STG) __builtin_amdgcn_s_barrier();
    // phase 1: stage B-rounds of tile t+3, compute mh=1 quadrant (B held in regs)
    if constexpr (STG) {
      gload_lds16(gbase[2] + stoff, smem + sslot + lbase[2]);
      gload_lds16(gbase[3] + stoff, smem + sslot + lbase[3]);
    }
#pragma unroll
    for (int m = 0; m < 4; ++m) af[m] = *(const bf16x8*)(smem + slot + aoff[4 + m]);
    __builtin_amdgcn_s_setprio(1);
#pragma unroll
    for (int m = 0; m < 4; ++m)
#pragma unroll
      for (int n = 0; n < 4; ++n)
        acc[4 + m][n] = __builtin_amdgcn_mfma_f32_16x16x32_bf16(af[m], bfr[n], acc[4 + m][n], 0, 0, 0);
    __builtin_amdgcn_s_setprio(0);
  } else {
    // single phase: 16 MFMA
    if constexpr (STG) {
      gload_lds16(gbase[0] + stoff, smem + sslot + lbase[0]);
      gload_lds16(gbase[1] + stoff, smem + sslot + lbase[1]);
      gload_lds16(gbase[2] + stoff, smem + sslot + lbase[2]);
    }
#pragma unroll
    for (int n = 0; n < 4; ++n) bfr[n] = *(const bf16x8*)(smem + slot + boff[n]);
#pragma unroll
    for (int m = 0; m < 4; ++m) af[m] = *(const bf16x8*)(smem + slot + aoff[m]);
    __builtin_amdgcn_s_setprio(1);
#pragma unroll
    for (int m = 0; m < 4; ++m)
#pragma unroll
      for (int n = 0; n < 4; ++n)
        acc[m][n] = __builtin_amdgcn_mfma_f32_16x16x32_bf16(af[m], bfr[n], acc[m][n], 0, 0, 0);
    __builtin_amdgcn_s_setprio(0);
  }
}

template <int TM, int EPI>
__device__ __forceinline__ void gemm_core(
    const bf16_t* __restrict__ A, const bf16_t* __restrict__ B,
    void* __restrict__ Cout, int M, int N, int K,
    int row0, int col0, bool causal, float scale, char* smem)
{
  constexpr int BM = TM * 32;
  constexpr int LPT_A = BM / 128;        // staging rounds for A (8KB each)
  constexpr int LPT = LPT_A + 2;         // + 2 rounds for B (256 rows)
  constexpr int ABYTES = BM * 64;        // A bytes per slot
  constexpr int SLOT = (BM + 256) * 64;  // slot bytes

  const int tid = threadIdx.x;
  const int w = tid >> 6, lane = tid & 63;
  const int wr = w >> 2, wc = w & 3;

  int Keff = K;
  if (EPI == EP_F32 && causal) Keff = min(K, row0 + BM);
  const int nt = Keff >> 5;

  // --- staging addresses (pre-swizzled global source, linear LDS dest) ---
  const char* gbase[LPT];
  int lbase[LPT];
  {
    const int sd = (tid & 3) ^ ((tid >> 3) & 3);  // swizzled k-slot (involution)
    const int rrow = tid >> 2;                    // 0..127
#pragma unroll
    for (int r = 0; r < LPT; ++r) {
      const bool isA = (r < LPT_A);
      const int rr = isA ? r : (r - LPT_A);
      const int R = rr * 128 + rrow;
      const int grow = (isA ? row0 : col0) + R;
      const bf16_t* op = isA ? A : B;
      gbase[r] = (const char*)(op + (size_t)grow * K) + sd * 16;
      lbase[r] = (isA ? 0 : ABYTES) + rr * 8192 + w * 1024;  // wave-uniform
    }
  }

  // --- fragment read offsets (swizzled, matches source pre-swizzle) ---
  const int fl = lane & 15;
  const int arow_off = fl * 64 + (((lane >> 4) ^ ((fl >> 1) & 3)) * 16);
  int aoff[TM], boff[4];
#pragma unroll
  for (int m = 0; m < TM; ++m) aoff[m] = (wr * (TM * 16) + m * 16) * 64 + arow_off;
#pragma unroll
  for (int n = 0; n < 4; ++n) boff[n] = ABYTES + (wc * 64 + n * 16) * 64 + arow_off;

  f32x4 acc[TM][4] = {};

  // --- prologue: stage tiles 0..2 ---
  const int npro = nt < 3 ? nt : 3;
  for (int t = 0; t < npro; ++t)
#pragma unroll
    for (int r = 0; r < LPT; ++r)
      gload_lds16(gbase[r] + (size_t)t * 64, smem + (t & 3) * SLOT + lbase[r]);

  // --- main loop: compute tile t, stage tile t+3 ---
  const int nmain = nt - 3;
  for (int t = 0; t < nmain; ++t) {
    if constexpr (TM == 8) asm volatile("s_waitcnt vmcnt(8)" ::: "memory");
    else                   asm volatile("s_waitcnt vmcnt(6)" ::: "memory");
    __builtin_amdgcn_s_barrier();
    asm volatile("" ::: "memory");
    __builtin_amdgcn_sched_barrier(0);
    do_tile<TM, true>(smem, (t & 3) * SLOT, ((t + 3) & 3) * SLOT,
                      (size_t)(t + 3) * 64, gbase, lbase, aoff, boff, acc);
  }

  // --- drain: last (up to) 3 tiles, everything already staged ---
  asm volatile("s_waitcnt vmcnt(0)" ::: "memory");
  __builtin_amdgcn_s_barrier();
  asm volatile("" ::: "memory");
  __builtin_amdgcn_sched_barrier(0);
  for (int t = nmain > 0 ? nmain : 0; t < nt; ++t)
    do_tile<TM, false>(smem, (t & 3) * SLOT, 0, 0, gbase, lbase, aoff, boff, acc);

  // --- epilogue (C/D layout: col = lane&15, row = (lane>>4)*4 + i) ---
  const int cr = (lane >> 4) * 4;
  const int cc = lane & 15;
#pragma unroll
  for (int m = 0; m < TM; ++m) {
#pragma unroll
    for (int n = 0; n < 4; ++n) {
#pragma unroll
      for (int i = 0; i < 4; ++i) {
        const int r = row0 + wr * (TM * 16) + m * 16 + cr + i;
        const int c = col0 + wc * 64 + n * 16 + cc;
        float v = acc[m][n][i];
        if (EPI == EP_BF16) {
          ((bf16_t*)Cout)[(size_t)r * N + c] = (bf16_t)v;
        } else if (EPI == EP_SCORES) {
          v *= scale;
          if (causal && c > r) v = -INFINITY;
          ((float*)Cout)[(size_t)r * N + c] = v;
        } else {
          ((float*)Cout)[(size_t)r * N + c] = v;
        }
      }
    }
  }
}

template <int TM, int EPI>
__launch_bounds__(512, 2)
__global__ void gemm_k(const bf16_t* __restrict__ A, const bf16_t* __restrict__ B,
                       void* __restrict__ C, int M, int N, int K,
                       const int* __restrict__ maskflag, float scale) {
  extern __shared__ __align__(16) char smem[];
  const bool causal = (maskflag != nullptr) && (maskflag[0] == 0);
  constexpr int BM = TM * 32;
  const int ntn = N >> 8;
  const int wg = blockIdx.x;
  const int row0 = (wg / ntn) * BM, col0 = (wg % ntn) * 256;
  if (EPI == EP_SCORES && causal && col0 > row0 + BM - 1) return;  // block-uniform
  gemm_core<TM, EPI>(A, B, C, M, N, K, row0, col0, causal, scale, smem);
}

// fused QKV: one launch, 384 blocks (q:128, k:128, v:128), all K=2048, TM=8
__launch_bounds__(512, 2)
__global__ void qkv_k(const bf16_t* __restrict__ qe, const bf16_t* __restrict__ ie,
                      const bf16_t* __restrict__ WqT, const bf16_t* __restrict__ WkT,
                      const bf16_t* __restrict__ WvT,
                      bf16_t* __restrict__ q16, bf16_t* __restrict__ k16,
                      bf16_t* __restrict__ vT16) {
  extern __shared__ __align__(16) char smem[];
  int wg = blockIdx.x;
  const bf16_t *A, *B; bf16_t* C; int M, N;
  if (wg < 128)      { A = qe;  B = WqT; C = q16;  M = 4096; N = 2048; }
  else if (wg < 256) { A = ie;  B = WkT; C = k16;  M = 4096; N = 2048; wg -= 128; }
  else               { A = WvT; B = ie;  C = vT16; M = 2048; N = 4096; wg -= 256; }
  const int ntn = N >> 8;
  const int row0 = (wg / ntn) * 256, col0 = (wg % ntn) * 256;
  gemm_core<8, EP_BF16>(A, B, C, M, N, 2048, row0, col0, false, 1.f, smem);
}

// ---------------------------------------------------------------------------

__global__ void cvt_f32_bf16(const float* __restrict__ x, bf16_t* __restrict__ y, long n) {
  long i = ((long)blockIdx.x * blockDim.x + threadIdx.x) * 8;
  const long stride = (long)gridDim.x * blockDim.x * 8;
  for (; i < n; i += stride) {
    const float4 a = *(const float4*)(x + i);
    const float4 b = *(const float4*)(x + i + 4);
    bf16x8 o;
    o[0] = (__bf16)a.x; o[1] = (__bf16)a.y; o[2] = (__bf16)a.z; o[3] = (__bf16)a.w;
    o[4] = (__bf16)b.x; o[5] = (__bf16)b.y; o[6] = (__bf16)b.z; o[7] = (__bf16)b.w;
    *(bf16x8*)(y + i) = o;
  }
}

// WT[n][k] = (bf16) W[k][n]
__global__ void transpose_cvt(const float* __restrict__ W, bf16_t* __restrict__ WT, int Dm) {
  __shared__ float tile[32][33];
  const int bx = blockIdx.x, by = blockIdx.y;
  const int tx = threadIdx.x & 31, ty = threadIdx.x >> 5;
#pragma unroll
  for (int r = ty; r < 32; r += 8)
    tile[r][tx] = W[(size_t)(by * 32 + r) * Dm + bx * 32 + tx];
  __syncthreads();
#pragma unroll
  for (int r = ty; r < 32; r += 8)
    WT[(size_t)(bx * 32 + r) * Dm + by * 32 + tx] = (bf16_t)tile[tx][r];
}

// one block per row; causal-aware: reads only j <= row, writes all n (zeros above)
__global__ void softmax_rows(const float* __restrict__ Sc, bf16_t* __restrict__ P,
                             int n, const int* __restrict__ maskflag) {
  const int row = blockIdx.x;
  const int tid = threadIdx.x;
  const bool causal = maskflag[0] == 0;
  const int L = causal ? (row + 1) : n;
  const float* srow = Sc + (size_t)row * n;
  float v[16];
  float m = -INFINITY;
#pragma unroll
  for (int j = 0; j < 16; ++j) {
    const int idx = tid + j * 256;
    v[j] = (idx < L) ? srow[idx] : -INFINITY;
    m = fmaxf(m, v[j]);
  }
#pragma unroll
  for (int off = 32; off >= 1; off >>= 1) m = fmaxf(m, __shfl_xor(m, off));
  __shared__ float redm[4];
  __shared__ float reds[4];
  if ((tid & 63) == 0) redm[tid >> 6] = m;
  __syncthreads();
  m = fmaxf(fmaxf(redm[0], redm[1]), fmaxf(redm[2], redm[3]));
  float s = 0.f;
#pragma unroll
  for (int j = 0; j < 16; ++j) {
    v[j] = __expf(v[j] - m);   // exp(-inf - m) = 0 for masked entries
    s += v[j];
  }
#pragma unroll
  for (int off = 32; off >= 1; off >>= 1) s += __shfl_xor(s, off);
  if ((tid & 63) == 0) reds[tid >> 6] = s;
  __syncthreads();
  s = reds[0] + reds[1] + reds[2] + reds[3];
  const float inv = 1.f / s;
  bf16_t* prow = P + (size_t)row * n;
#pragma unroll
  for (int j = 0; j < 16; ++j) prow[tid + j * 256] = (bf16_t)(v[j] * inv);
}

extern "C" void kernel_launch(void* const* d_in, const int* in_sizes, int n_in,
                              void* d_out, int out_size, void* d_ws, size_t ws_size,
                              hipStream_t stream) {
  const float* ie = (const float*)d_in[0];
  const float* qe = (const float*)d_in[1];
  const float* Wq = (const float*)d_in[2];
  const float* Wk = (const float*)d_in[3];
  const float* Wv = (const float*)d_in[4];
  const int* mask = (const int*)d_in[5];
  float* out = (float*)d_out;

  const int S = 4096, D = 2048;
  char* ws = (char*)d_ws;
  const size_t MB = 1u << 20;
  bf16_t* q16  = (bf16_t*)(ws + 0 * MB);
  bf16_t* k16  = (bf16_t*)(ws + 16 * MB);
  bf16_t* vT16 = (bf16_t*)(ws + 32 * MB);
  bf16_t* qe16 = (bf16_t*)(ws + 48 * MB);
  bf16_t* ie16 = (bf16_t*)(ws + 64 * MB);
  bf16_t* WqT  = (bf16_t*)(ws + 80 * MB);
  bf16_t* WkT  = (bf16_t*)(ws + 88 * MB);
  bf16_t* WvT  = (bf16_t*)(ws + 96 * MB);
  float*  scores = (float*)(ws + 48 * MB);   // overlays qe16/ie16/W*T after QKV
  bf16_t* probs  = (bf16_t*)(ws + 112 * MB);

  // opt-in to >64KB dynamic LDS (idempotent, host-side, capture-safe)
  hipFuncSetAttribute(reinterpret_cast<const void*>(&qkv_k),
                      hipFuncAttributeMaxDynamicSharedMemorySize, 131072);
  hipFuncSetAttribute(reinterpret_cast<const void*>(&gemm_k<8, EP_SCORES>),
                      hipFuncAttributeMaxDynamicSharedMemorySize, 131072);
  hipFuncSetAttribute(reinterpret_cast<const void*>(&gemm_k<4, EP_F32>),
                      hipFuncAttributeMaxDynamicSharedMemorySize, 98304);

  // 1. casts + weight transposes
  cvt_f32_bf16<<<2048, 256, 0, stream>>>(qe, qe16, (long)S * D);
  cvt_f32_bf16<<<2048, 256, 0, stream>>>(ie, ie16, (long)S * D);
  transpose_cvt<<<dim3(D / 32, D / 32), 256, 0, stream>>>(Wq, WqT, D);
  transpose_cvt<<<dim3(D / 32, D / 32), 256, 0, stream>>>(Wk, WkT, D);
  transpose_cvt<<<dim3(D / 32, D / 32), 256, 0, stream>>>(Wv, WvT, D);

  // 2. fused QKV projections (q16, k16, vT16), one 384-block launch
  qkv_k<<<384, 512, 131072, stream>>>(qe16, ie16, WqT, WkT, WvT, q16, k16, vT16);

  // 3. scores = (q @ k^T) * 0.1, fp32, causal tiles skipped (no fill)
  gemm_k<8, EP_SCORES><<<256, 512, 131072, stream>>>(q16, k16, scores, S, S, D, mask, 0.1f);

  // 4. causal-aware row softmax -> bf16 probs (zeros above diagonal)
  softmax_rows<<<S, 256, 0, stream>>>(scores, probs, S, mask);

  // 5. out = probs @ v  (A=probs, Bt=vT16), K truncated at causal boundary
  gemm_k<4, EP_F32><<<256, 512, 98304, stream>>>(probs, vT16, out, S, D, S, mask, 1.f);
}